// Round 7
// baseline (118.487 us; speedup 1.0000x reference)
//
#include <hip/hip_runtime.h>
#include <hip/hip_bf16.h>

#define BS   8
#define NREL 16
#define NN   512
#define EMB  256

typedef float f32x4 __attribute__((ext_vector_type(4)));
typedef short s16x8 __attribute__((ext_vector_type(8)));

// f32 -> bf16 bits, round-to-nearest-even
__device__ __forceinline__ unsigned short f2bf_bits(float f) {
    union { float f; unsigned u; } v; v.f = f;
    unsigned r = (v.u + 0x7FFFu + ((v.u >> 16) & 1u)) >> 16;
    return (unsigned short)r;
}

// ---------------------------------------------------------------------------
// K0: transpose W_r[16][256][256] + W_0[256][256] -> wT[17][h][d] bf16
// ---------------------------------------------------------------------------
__global__ __launch_bounds__(256) void k0_transpose(
        const float* __restrict__ Wr, const float* __restrict__ W0,
        unsigned short* __restrict__ wT) {
    __shared__ float tile[32][33];
    int bid = blockIdx.x;
    int rel = bid / 64;          // 0..16
    int t   = bid % 64;
    int d0  = (t & 7) * 32;
    int h0  = (t >> 3) * 32;
    int tx  = threadIdx.x & 31;
    int ty  = threadIdx.x >> 5;  // 0..7
    const float* src = (rel < NREL) ? (Wr + rel * (EMB * EMB)) : W0;
#pragma unroll
    for (int k = 0; k < 4; ++k) {
        int d = d0 + ty + k * 8;
        tile[ty + k * 8][tx] = src[d * EMB + h0 + tx];
    }
    __syncthreads();
#pragma unroll
    for (int k = 0; k < 4; ++k) {
        int h = h0 + ty + k * 8;
        wT[(rel * EMB + h) * EMB + d0 + tx] = f2bf_bits(tile[tx][ty + k * 8]);
    }
}

// ---------------------------------------------------------------------------
// K0b: convert F[8][512][256] f32 -> Fbf bf16 row-major
// ---------------------------------------------------------------------------
__global__ __launch_bounds__(256) void k0b_convF(
        const float* __restrict__ F, unsigned short* __restrict__ Fbf) {
    long i = ((long)blockIdx.x * 256 + threadIdx.x) * 8;
    f32x4 x0 = *(const f32x4*)(F + i);
    f32x4 x1 = *(const f32x4*)(F + i + 4);
    s16x8 v;
    v[0] = (short)f2bf_bits(x0[0]); v[1] = (short)f2bf_bits(x0[1]);
    v[2] = (short)f2bf_bits(x0[2]); v[3] = (short)f2bf_bits(x0[3]);
    v[4] = (short)f2bf_bits(x1[0]); v[5] = (short)f2bf_bits(x1[1]);
    v[6] = (short)f2bf_bits(x1[2]); v[7] = (short)f2bf_bits(x1[3]);
    *(s16x8*)(Fbf + i) = v;
}

// ---------------------------------------------------------------------------
// K1: FW[b][rel][m][h] = sum_d F[b][m][d] * W[rel][d][h]
//   D[h][m] = wT(A) x Fbf(B), MFMA 16x16x32 bf16, all-bf16 operand loads.
//   rel<16  -> FW fragment-major: [(b*16+rel)*64 + m/8][h][m%8] bf16
//   rel==16 -> F2f f32 row-major [b][n][h]
// ---------------------------------------------------------------------------
__global__ __launch_bounds__(256) void k1_fw(
        const unsigned short* __restrict__ Fbf, const unsigned short* __restrict__ wT,
        unsigned short* __restrict__ FW, float* __restrict__ F2f) {
    int bid = blockIdx.x;
    int b   = bid & 7;
    int q   = bid >> 3;          // 0..135
    int rel = q % 17;
    int mt  = q / 17;            // 0..7
    int tid = threadIdx.x;
    int w   = tid >> 6;          // 0..3
    int l   = tid & 63;
    int lg  = l >> 4;            // 0..3
    int lr  = l & 15;

    int h0 = w * 64;             // wave's 64 h-rows (M-dim)
    int m0 = mt * 64;            // block's 64 m-cols (N-dim)

    const unsigned short* wt = wT + rel * (EMB * EMB);
    const unsigned short* Fb = Fbf + (long)b * (NN * EMB);

    f32x4 acc[4][4];
#pragma unroll
    for (int i = 0; i < 4; ++i)
#pragma unroll
        for (int j = 0; j < 4; ++j) acc[i][j] = (f32x4){0.f, 0.f, 0.f, 0.f};

#pragma unroll 2
    for (int kk = 0; kk < EMB; kk += 32) {
        s16x8 afrag[4];
#pragma unroll
        for (int hi = 0; hi < 4; ++hi) {
            int row = h0 + hi * 16 + lr;
            afrag[hi] = *(const s16x8*)(wt + row * EMB + kk + lg * 8);
        }
        s16x8 bfrag[4];
#pragma unroll
        for (int bi = 0; bi < 4; ++bi) {
            int m = m0 + bi * 16 + lr;
            bfrag[bi] = *(const s16x8*)(Fb + m * EMB + kk + lg * 8);
        }
#pragma unroll
        for (int hi = 0; hi < 4; ++hi)
#pragma unroll
            for (int bi = 0; bi < 4; ++bi)
                acc[hi][bi] = __builtin_amdgcn_mfma_f32_16x16x32_bf16(
                    afrag[hi], bfrag[bi], acc[hi][bi], 0, 0, 0);
    }

    // Epilogue: D rows = h, cols = m.  C layout: col = lane&15, row = (lane>>4)*4+j
#pragma unroll
    for (int hi = 0; hi < 4; ++hi) {
#pragma unroll
        for (int bi = 0; bi < 4; ++bi) {
            int m  = m0 + bi * 16 + lr;
            int kg = m >> 3, ko = m & 7;
#pragma unroll
            for (int j = 0; j < 4; ++j) {
                int h = h0 + hi * 16 + lg * 4 + j;
                if (rel < NREL)
                    FW[(long)((b * 16 + rel) * 64 + kg) * 2048 + h * 8 + ko] =
                        f2bf_bits(acc[hi][bi][j]);
                else
                    F2f[((long)b * NN + m) * EMB + h] = acc[hi][bi][j];
            }
        }
    }
}

// ---------------------------------------------------------------------------
// K2: part[rg][b][n][h] = sum_{r in rg(2 rels)} sum_m adj[b][r][n][m]*FW[b][r][m][h]
//   grid 512 = 8b (XCD-grouped) x 8nt(64 rows) x 8rg(2 rels)
//   block 512 thr = 8 waves = 4 wr x 2 wc.  Wave tile: 16 rows x 256 cols,
//   acc[16].  wc splits the 32 K-slices by parity (slice = 2i+wc) -> adjacency
//   read EXACTLY once (no column duplication).  Per iter the block stages a
//   PAIR of slices (32KB) double-buffered (64KB LDS).  Reg-staged T14
//   pipeline, raw s_barrier + lgkmcnt(0) only (no vmcnt(0) in loop).
//   Epilogue: wc=1 partial acc added to wc=0 via LDS, wc=0 stores part.
// ---------------------------------------------------------------------------
__global__ __launch_bounds__(512, 4) void k2_main(
        const float* __restrict__ adj, const unsigned short* __restrict__ FW,
        float* __restrict__ part) {
    __shared__ unsigned short Blds[2][2][8192];   // [buf][slice parity][16KB] = 64KB
    int bid = blockIdx.x;
    int b   = bid & 7;
    int t   = bid >> 3;          // 0..63
    int nt  = t & 7;
    int rg  = t >> 3;            // 0..7
    int tid = threadIdx.x;
    int w   = tid >> 6;          // 0..7
    int l   = tid & 63;
    int lg  = l >> 4, lr = l & 15;
    int wr  = w >> 1;            // 0..3
    int wc  = w & 1;             // 0..1 : K-slice parity

    int nrow = nt * 64 + wr * 16;     // wave's 16 output rows

    f32x4 acc[16];
#pragma unroll
    for (int i = 0; i < 16; ++i) acc[i] = (f32x4){0.f, 0.f, 0.f, 0.f};

    // adjacency: row = nrow+lr, 32-float chunk at lg*8 within each slice
    const float* adj_base =
        adj + (((long)(b * 16 + rg * 2)) * NN + nrow + lr) * NN + lg * 8;
    // FW staging: this thread stages slice 2p+(tid>>8), 64B chunk at (tid&255)*32
    int sp = tid >> 8;                 // slice parity this thread stages
    const unsigned short* fw_s =
        FW + (long)(b * 16 + rg * 2) * 131072 + (tid & 255) * 32;
    unsigned short* ldst0 = &Blds[0][sp][(tid & 255) * 32];
    unsigned short* ldst1 = &Blds[1][sp][(tid & 255) * 32];

    // staging regs: one slice-pair at a time (4 x s16x8 = 64B)
    s16x8 fwr0, fwr1, fwr2, fwr3;
    // adjacency regs: 2 slots (parity of i)
    f32x4 ax0, ay0, ax1, ay1;

    // ---- prologue ----
    {   // load pair 0 (slice sp), write buf0
        long off = (long)(sp >> 4) * 131072 + (sp & 15) * 8192;   // sp in {0,1}
        const unsigned short* src = fw_s + off;
        fwr0 = *(const s16x8*)(src);
        fwr1 = *(const s16x8*)(src + 8);
        fwr2 = *(const s16x8*)(src + 16);
        fwr3 = *(const s16x8*)(src + 24);
        *(s16x8*)(ldst0)      = fwr0;
        *(s16x8*)(ldst0 + 8)  = fwr1;
        *(s16x8*)(ldst0 + 16) = fwr2;
        *(s16x8*)(ldst0 + 24) = fwr3;
    }
    {   // adjacency slice wc (used at i=0)
        int sl = wc;
        const float* p = adj_base + (long)(sl >> 4) * (NN * NN) + (sl & 15) * 32;
        ax0 = *(const f32x4*)p;
        ay0 = *(const f32x4*)(p + 4);
    }
    {   // load pair 1 regs (slices 2+sp)
        int sl = 2 + sp;
        long off = (long)(sl >> 4) * 131072 + (sl & 15) * 8192;
        const unsigned short* src = fw_s + off;
        fwr0 = *(const s16x8*)(src);
        fwr1 = *(const s16x8*)(src + 8);
        fwr2 = *(const s16x8*)(src + 16);
        fwr3 = *(const s16x8*)(src + 24);
    }
    asm volatile("s_waitcnt lgkmcnt(0)" ::: "memory");
    __builtin_amdgcn_sched_barrier(0);
    __builtin_amdgcn_s_barrier();
    asm volatile("" ::: "memory");

#pragma unroll
    for (int i = 0; i < 16; ++i) {
        // 1. issue adjacency slice 2(i+1)+wc into the other reg slot
        if (i + 1 < 16) {
            int sl = 2 * (i + 1) + wc;
            const float* p =
                adj_base + (long)(sl >> 4) * (NN * NN) + (sl & 15) * 32;
            if ((i & 1) == 0) { ax1 = *(const f32x4*)p; ay1 = *(const f32x4*)(p + 4); }
            else              { ax0 = *(const f32x4*)p; ay0 = *(const f32x4*)(p + 4); }
        }

        // 2. compute slice 2i+wc from Blds[i&1][wc]
        f32x4 x0 = ((i & 1) == 0) ? ax0 : ax1;
        f32x4 x1 = ((i & 1) == 0) ? ay0 : ay1;
        s16x8 a;
        a[0] = (short)f2bf_bits(x0[0]); a[1] = (short)f2bf_bits(x0[1]);
        a[2] = (short)f2bf_bits(x0[2]); a[3] = (short)f2bf_bits(x0[3]);
        a[4] = (short)f2bf_bits(x1[0]); a[5] = (short)f2bf_bits(x1[1]);
        a[6] = (short)f2bf_bits(x1[2]); a[7] = (short)f2bf_bits(x1[3]);
        const unsigned short* bl = &Blds[i & 1][wc][lg * 2048];
#pragma unroll
        for (int f = 0; f < 16; ++f) {
            s16x8 bf = *(const s16x8*)(bl + (f * 16 + lr) * 8);
            acc[f] = __builtin_amdgcn_mfma_f32_16x16x32_bf16(a, bf, acc[f], 0, 0, 0);
        }
        asm volatile("" ::: "memory");   // ds_reads above, ds_writes below

        // 3. ds_write pair i+1 into buf[(i+1)&1]; 4. issue pair i+2 regs
        if (i + 1 < 16) {
            unsigned short* dst = ((i + 1) & 1) ? ldst1 : ldst0;
            *(s16x8*)(dst)      = fwr0;
            *(s16x8*)(dst + 8)  = fwr1;
            *(s16x8*)(dst + 16) = fwr2;
            *(s16x8*)(dst + 24) = fwr3;
            if (i + 2 < 16) {
                int sl = 2 * (i + 2) + sp;
                long off = (long)(sl >> 4) * 131072 + (sl & 15) * 8192;
                const unsigned short* src = fw_s + off;
                fwr0 = *(const s16x8*)(src);
                fwr1 = *(const s16x8*)(src + 8);
                fwr2 = *(const s16x8*)(src + 16);
                fwr3 = *(const s16x8*)(src + 24);
            }
            asm volatile("s_waitcnt lgkmcnt(0)" ::: "memory");
            __builtin_amdgcn_sched_barrier(0);
            __builtin_amdgcn_s_barrier();
            asm volatile("" ::: "memory");
        }
    }

    // ---- cross-wc reduce via LDS (stride-64 b32 scatter: 2-way banks, free)
    __syncthreads();
    float* lf = (float*)Blds;          // 16384 floats = 64KB
    if (wc == 1) {
#pragma unroll
        for (int f = 0; f < 16; ++f)
#pragma unroll
            for (int j = 0; j < 4; ++j)
                lf[wr * 4096 + (f * 4 + j) * 64 + l] = acc[f][j];
    }
    __syncthreads();
    if (wc == 0) {
        float* pp = part + ((long)rg * BS + b) * (NN * EMB);
#pragma unroll
        for (int f = 0; f < 16; ++f) {
            int h = f * 16 + lr;
#pragma unroll
            for (int j = 0; j < 4; ++j) {
                int n = nrow + lg * 4 + j;
                float v = acc[f][j] + lf[wr * 4096 + (f * 4 + j) * 64 + l];
                pp[(long)n * EMB + h] = v;
            }
        }
    }
}

// ---------------------------------------------------------------------------
// K3: out = relu(sum over 8 rg slices + F2f), vectorized f32x4
// ---------------------------------------------------------------------------
__global__ __launch_bounds__(256) void k3_reduce(
        const float* __restrict__ part, const float* __restrict__ F2f,
        float* __restrict__ out) {
    const long PS = (long)BS * NN * EMB;   // 1,048,576 floats per rg slice
    long i = ((long)blockIdx.x * 256 + threadIdx.x) * 4;
    f32x4 s = *(const f32x4*)(part + i);
#pragma unroll
    for (int rg = 1; rg < 8; ++rg)
        s += *(const f32x4*)(part + i + (long)rg * PS);
    s += *(const f32x4*)(F2f + i);
    f32x4 r;
#pragma unroll
    for (int j = 0; j < 4; ++j) r[j] = s[j] > 0.f ? s[j] : 0.f;
    *(f32x4*)(out + i) = r;
}

// ---------------------------------------------------------------------------
extern "C" void kernel_launch(void* const* d_in, const int* in_sizes, int n_in,
                              void* d_out, int out_size, void* d_ws, size_t ws_size,
                              hipStream_t stream) {
    const float* F   = (const float*)d_in[0];   // [8][512][256]
    const float* adj = (const float*)d_in[1];   // [8][16][512][512]
    const float* Wr  = (const float*)d_in[2];   // [16][256][256]
    const float* W0  = (const float*)d_in[3];   // [256][256]
    float* out = (float*)d_out;                 // [8][512][256]

    unsigned short* wT  = (unsigned short*)d_ws;             // 17*256*256 bf16
    unsigned short* Fbf = wT + 17 * 256 * 256;               // 8*512*256 bf16
    unsigned short* FW  = Fbf + (long)8 * 512 * 256;         // 8*16*64*2048 bf16
    float* F2f  = (float*)(FW + (long)8 * 16 * 64 * 2048);   // 8*512*256 f32
    float* part = F2f + (long)8 * 512 * 256;                 // 8*8*512*256 f32

    k0_transpose<<<17 * 64, 256, 0, stream>>>(Wr, W0, wT);
    k0b_convF<<<512, 256, 0, stream>>>(F, Fbf);
    k1_fw<<<1088, 256, 0, stream>>>(Fbf, wT, FW, F2f);
    k2_main<<<512, 512, 0, stream>>>(adj, FW, part);
    k3_reduce<<<1024, 256, 0, stream>>>(part, F2f, out);
}

// Round 8
// 105.670 us; speedup vs baseline: 1.1213x; 1.1213x over previous
//
#include <hip/hip_runtime.h>
#include <hip/hip_bf16.h>

#define BS   8
#define NREL 16
#define NN   512
#define EMB  256

typedef float f32x4 __attribute__((ext_vector_type(4)));
typedef short s16x8 __attribute__((ext_vector_type(8)));

// f32 -> bf16 bits, round-to-nearest-even (cold kernels)
__device__ __forceinline__ unsigned short f2bf_bits(float f) {
    union { float f; unsigned u; } v; v.f = f;
    unsigned r = (v.u + 0x7FFFu + ((v.u >> 16) & 1u)) >> 16;
    return (unsigned short)r;
}

// hw cvt path (compiler emits v_cvt_pk_bf16_f32 when paired)
__device__ __forceinline__ unsigned short f2bf_hw(float f) {
    union { __hip_bfloat16 h; unsigned short u; } v;
    v.h = __float2bfloat16(f);
    return v.u;
}

// ---------------------------------------------------------------------------
// K0: transpose W_r[16][256][256] + W_0[256][256] -> wT[17][h][d] bf16
// ---------------------------------------------------------------------------
__global__ __launch_bounds__(256) void k0_transpose(
        const float* __restrict__ Wr, const float* __restrict__ W0,
        unsigned short* __restrict__ wT) {
    __shared__ float tile[32][33];
    int bid = blockIdx.x;
    int rel = bid / 64;          // 0..16
    int t   = bid % 64;
    int d0  = (t & 7) * 32;
    int h0  = (t >> 3) * 32;
    int tx  = threadIdx.x & 31;
    int ty  = threadIdx.x >> 5;  // 0..7
    const float* src = (rel < NREL) ? (Wr + rel * (EMB * EMB)) : W0;
#pragma unroll
    for (int k = 0; k < 4; ++k) {
        int d = d0 + ty + k * 8;
        tile[ty + k * 8][tx] = src[d * EMB + h0 + tx];
    }
    __syncthreads();
#pragma unroll
    for (int k = 0; k < 4; ++k) {
        int h = h0 + ty + k * 8;
        wT[(rel * EMB + h) * EMB + d0 + tx] = f2bf_bits(tile[tx][ty + k * 8]);
    }
}

// ---------------------------------------------------------------------------
// K0b: convert F[8][512][256] f32 -> Fbf bf16 row-major
// ---------------------------------------------------------------------------
__global__ __launch_bounds__(256) void k0b_convF(
        const float* __restrict__ F, unsigned short* __restrict__ Fbf) {
    long i = ((long)blockIdx.x * 256 + threadIdx.x) * 8;
    f32x4 x0 = *(const f32x4*)(F + i);
    f32x4 x1 = *(const f32x4*)(F + i + 4);
    s16x8 v;
    v[0] = (short)f2bf_bits(x0[0]); v[1] = (short)f2bf_bits(x0[1]);
    v[2] = (short)f2bf_bits(x0[2]); v[3] = (short)f2bf_bits(x0[3]);
    v[4] = (short)f2bf_bits(x1[0]); v[5] = (short)f2bf_bits(x1[1]);
    v[6] = (short)f2bf_bits(x1[2]); v[7] = (short)f2bf_bits(x1[3]);
    *(s16x8*)(Fbf + i) = v;
}

// ---------------------------------------------------------------------------
// K1: FW[b][rel][m][h] = sum_d F[b][m][d] * W[rel][d][h]
//   D[h][m] = wT(A) x Fbf(B), MFMA 16x16x32 bf16, all-bf16 operand loads.
//   rel<16  -> FW fragment-major: [(b*16+rel)*64 + m/8][h][m%8] bf16
//   rel==16 -> F2f f32 row-major [b][n][h]
// ---------------------------------------------------------------------------
__global__ __launch_bounds__(256) void k1_fw(
        const unsigned short* __restrict__ Fbf, const unsigned short* __restrict__ wT,
        unsigned short* __restrict__ FW, float* __restrict__ F2f) {
    int bid = blockIdx.x;
    int b   = bid & 7;
    int q   = bid >> 3;          // 0..135
    int rel = q % 17;
    int mt  = q / 17;            // 0..7
    int tid = threadIdx.x;
    int w   = tid >> 6;          // 0..3
    int l   = tid & 63;
    int lg  = l >> 4;            // 0..3
    int lr  = l & 15;

    int h0 = w * 64;             // wave's 64 h-rows (M-dim)
    int m0 = mt * 64;            // block's 64 m-cols (N-dim)

    const unsigned short* wt = wT + rel * (EMB * EMB);
    const unsigned short* Fb = Fbf + (long)b * (NN * EMB);

    f32x4 acc[4][4];
#pragma unroll
    for (int i = 0; i < 4; ++i)
#pragma unroll
        for (int j = 0; j < 4; ++j) acc[i][j] = (f32x4){0.f, 0.f, 0.f, 0.f};

#pragma unroll 2
    for (int kk = 0; kk < EMB; kk += 32) {
        s16x8 afrag[4];
#pragma unroll
        for (int hi = 0; hi < 4; ++hi) {
            int row = h0 + hi * 16 + lr;
            afrag[hi] = *(const s16x8*)(wt + row * EMB + kk + lg * 8);
        }
        s16x8 bfrag[4];
#pragma unroll
        for (int bi = 0; bi < 4; ++bi) {
            int m = m0 + bi * 16 + lr;
            bfrag[bi] = *(const s16x8*)(Fb + m * EMB + kk + lg * 8);
        }
#pragma unroll
        for (int hi = 0; hi < 4; ++hi)
#pragma unroll
            for (int bi = 0; bi < 4; ++bi)
                acc[hi][bi] = __builtin_amdgcn_mfma_f32_16x16x32_bf16(
                    afrag[hi], bfrag[bi], acc[hi][bi], 0, 0, 0);
    }

    // Epilogue: D rows = h, cols = m.  C layout: col = lane&15, row = (lane>>4)*4+j
#pragma unroll
    for (int hi = 0; hi < 4; ++hi) {
#pragma unroll
        for (int bi = 0; bi < 4; ++bi) {
            int m  = m0 + bi * 16 + lr;
            int kg = m >> 3, ko = m & 7;
#pragma unroll
            for (int j = 0; j < 4; ++j) {
                int h = h0 + hi * 16 + lg * 4 + j;
                if (rel < NREL)
                    FW[(long)((b * 16 + rel) * 64 + kg) * 2048 + h * 8 + ko] =
                        f2bf_bits(acc[hi][bi][j]);
                else
                    F2f[((long)b * NN + m) * EMB + h] = acc[hi][bi][j];
            }
        }
    }
}

// ---------------------------------------------------------------------------
// K2: part[rg][b][n][h] = sum_{r in rg(2 rels)} sum_m adj[b][r][n][m]*FW[b][r][m][h]
//   grid 512 = 8b (XCD-grouped) x 8nt(64 rows) x 8rg(2 rels)
//   block 256 thr = 4 waves (2 wr x 2 wc).  Wave tile: 32 rows x 256 cols,
//   acc[2][16] (128 VGPR).  wc splits the 32 K-slices by parity -> adjacency
//   read exactly once; each ds_read_b128 feeds 2 MFMAs.
//   Staging: wave w stages parity (w&1), half (w>>1): 8 lane-contiguous 1KB
//   chunks (conflict-free ds_write_b128, fully-coalesced global loads).
//   Reg-staged T14 pipeline: one raw s_barrier + lgkmcnt(0) per iter,
//   no vmcnt(0) in the loop.
// ---------------------------------------------------------------------------
__global__ __launch_bounds__(256, 2) void k2_main(
        const float* __restrict__ adj, const unsigned short* __restrict__ FW,
        float* __restrict__ part) {
    __shared__ unsigned short Blds[2][2][8192];   // [buf][parity][16KB] = 64KB
    int bid = blockIdx.x;
    int b   = bid & 7;
    int t   = bid >> 3;          // 0..63
    int nt  = t & 7;
    int rg  = t >> 3;            // 0..7
    int tid = threadIdx.x;
    int w   = tid >> 6;          // 0..3
    int l   = tid & 63;
    int lg  = l >> 4, lr = l & 15;
    int wr  = w >> 1;            // 0..1 : 32-row group
    int wc  = w & 1;             // 0..1 : K-slice parity

    int nrow = nt * 64 + wr * 32;     // wave's 32 output rows

    f32x4 acc0[16], acc1[16];
#pragma unroll
    for (int i = 0; i < 16; ++i) {
        acc0[i] = (f32x4){0.f, 0.f, 0.f, 0.f};
        acc1[i] = (f32x4){0.f, 0.f, 0.f, 0.f};
    }

    // adjacency: row groups nrow+lr and nrow+16+lr, 32-float chunk at lg*8
    const float* adjb0 =
        adj + (((long)(b * 16 + rg * 2)) * NN + nrow + lr) * NN + lg * 8;
    const float* adjb1 = adjb0 + 16 * NN;
    const unsigned short* fwb = FW + (long)(b * 16 + rg * 2) * 131072;

    // staging: wave w -> parity sp=(w&1), half hf=(w>>1); lane-contiguous 16B
    int sp = w & 1;
    int hf = w >> 1;
    const unsigned short* fw_s = fwb + hf * 4096 + l * 8;
    unsigned short* st0 = &Blds[0][sp][hf * 4096 + l * 8];
    unsigned short* st1 = &Blds[1][sp][hf * 4096 + l * 8];

    s16x8 fwr[8];                       // one slice-half in flight (128B/thread)
    f32x4 ax[2][2], ay[2][2];           // [slot][row group]

    // slice offset in shorts: rel = sl>>4, k16 = sl&15
#define SOFF(sl) ((long)((sl) >> 4) * 131072 + ((sl) & 15) * 8192)

    // ---- prologue ----
    {   // pair 0 (slice sp): load regs, write buf0
        const unsigned short* s = fw_s + SOFF(sp);
#pragma unroll
        for (int k = 0; k < 8; ++k) fwr[k] = *(const s16x8*)(s + k * 512);
#pragma unroll
        for (int k = 0; k < 8; ++k) *(s16x8*)(st0 + k * 512) = fwr[k];
    }
    {   // adjacency slice wc -> slot 0 (both row groups)
        const float* p0 = adjb0 + wc * 32;
        const float* p1 = adjb1 + wc * 32;
        ax[0][0] = *(const f32x4*)p0; ay[0][0] = *(const f32x4*)(p0 + 4);
        ax[0][1] = *(const f32x4*)p1; ay[0][1] = *(const f32x4*)(p1 + 4);
    }
    {   // pair 1 regs (slice 2+sp)
        const unsigned short* s = fw_s + SOFF(2 + sp);
#pragma unroll
        for (int k = 0; k < 8; ++k) fwr[k] = *(const s16x8*)(s + k * 512);
    }
    asm volatile("s_waitcnt lgkmcnt(0)" ::: "memory");
    __builtin_amdgcn_sched_barrier(0);
    __builtin_amdgcn_s_barrier();
    asm volatile("" ::: "memory");

#pragma unroll
    for (int i = 0; i < 16; ++i) {
        // 1. issue adjacency slice 2(i+1)+wc into the other slot
        if (i + 1 < 16) {
            int sl = 2 * (i + 1) + wc;
            long ao = (long)(sl >> 4) * (NN * NN) + (sl & 15) * 32;
            const float* p0 = adjb0 + ao;
            const float* p1 = adjb1 + ao;
            if (((i + 1) & 1) == 0) {
                ax[0][0] = *(const f32x4*)p0; ay[0][0] = *(const f32x4*)(p0 + 4);
                ax[0][1] = *(const f32x4*)p1; ay[0][1] = *(const f32x4*)(p1 + 4);
            } else {
                ax[1][0] = *(const f32x4*)p0; ay[1][0] = *(const f32x4*)(p0 + 4);
                ax[1][1] = *(const f32x4*)p1; ay[1][1] = *(const f32x4*)(p1 + 4);
            }
        }

        // 2. compute slice 2i+wc from Blds[i&1][wc]
        f32x4 x00 = ax[i & 1][0], x01 = ay[i & 1][0];
        f32x4 x10 = ax[i & 1][1], x11 = ay[i & 1][1];
        s16x8 a0, a1;
        a0[0] = (short)f2bf_hw(x00[0]); a0[1] = (short)f2bf_hw(x00[1]);
        a0[2] = (short)f2bf_hw(x00[2]); a0[3] = (short)f2bf_hw(x00[3]);
        a0[4] = (short)f2bf_hw(x01[0]); a0[5] = (short)f2bf_hw(x01[1]);
        a0[6] = (short)f2bf_hw(x01[2]); a0[7] = (short)f2bf_hw(x01[3]);
        a1[0] = (short)f2bf_hw(x10[0]); a1[1] = (short)f2bf_hw(x10[1]);
        a1[2] = (short)f2bf_hw(x10[2]); a1[3] = (short)f2bf_hw(x10[3]);
        a1[4] = (short)f2bf_hw(x11[0]); a1[5] = (short)f2bf_hw(x11[1]);
        a1[6] = (short)f2bf_hw(x11[2]); a1[7] = (short)f2bf_hw(x11[3]);

        const unsigned short* bl = &Blds[i & 1][wc][lg * 2048];
#pragma unroll
        for (int f = 0; f < 16; ++f) {
            s16x8 bf = *(const s16x8*)(bl + (f * 16 + lr) * 8);
            acc0[f] = __builtin_amdgcn_mfma_f32_16x16x32_bf16(a0, bf, acc0[f], 0, 0, 0);
            acc1[f] = __builtin_amdgcn_mfma_f32_16x16x32_bf16(a1, bf, acc1[f], 0, 0, 0);
        }
        asm volatile("" ::: "memory");   // ds_reads above, ds_writes below

        // 3. ds_write pair i+1; 4. issue pair i+2 regs; barrier
        if (i + 1 < 16) {
            unsigned short* dst = ((i + 1) & 1) ? st1 : st0;
#pragma unroll
            for (int k = 0; k < 8; ++k) *(s16x8*)(dst + k * 512) = fwr[k];
            if (i + 2 < 16) {
                const unsigned short* s = fw_s + SOFF(2 * (i + 2) + sp);
#pragma unroll
                for (int k = 0; k < 8; ++k) fwr[k] = *(const s16x8*)(s + k * 512);
            }
            asm volatile("s_waitcnt lgkmcnt(0)" ::: "memory");
            __builtin_amdgcn_sched_barrier(0);
            __builtin_amdgcn_s_barrier();
            asm volatile("" ::: "memory");
        }
    }
#undef SOFF

    // ---- cross-wc reduce via LDS (stride-64 floats: 2 lanes/bank, free)
    __syncthreads();
    float* lf = (float*)Blds;          // 16384 floats = 64KB
    if (wc == 1) {
#pragma unroll
        for (int g = 0; g < 2; ++g)
#pragma unroll
            for (int f = 0; f < 16; ++f)
#pragma unroll
                for (int j = 0; j < 4; ++j)
                    lf[wr * 8192 + ((g * 16 + f) * 4 + j) * 64 + l] =
                        g ? acc1[f][j] : acc0[f][j];
    }
    __syncthreads();
    if (wc == 0) {
        float* pp = part + ((long)rg * BS + b) * (NN * EMB);
#pragma unroll
        for (int g = 0; g < 2; ++g)
#pragma unroll
            for (int f = 0; f < 16; ++f) {
                int h = f * 16 + lr;
#pragma unroll
                for (int j = 0; j < 4; ++j) {
                    int n = nrow + g * 16 + lg * 4 + j;
                    float v = (g ? acc1[f][j] : acc0[f][j]) +
                              lf[wr * 8192 + ((g * 16 + f) * 4 + j) * 64 + l];
                    pp[(long)n * EMB + h] = v;
                }
            }
    }
}

// ---------------------------------------------------------------------------
// K3: out = relu(sum over 8 rg slices + F2f), vectorized f32x4
// ---------------------------------------------------------------------------
__global__ __launch_bounds__(256) void k3_reduce(
        const float* __restrict__ part, const float* __restrict__ F2f,
        float* __restrict__ out) {
    const long PS = (long)BS * NN * EMB;   // 1,048,576 floats per rg slice
    long i = ((long)blockIdx.x * 256 + threadIdx.x) * 4;
    f32x4 s = *(const f32x4*)(part + i);
#pragma unroll
    for (int rg = 1; rg < 8; ++rg)
        s += *(const f32x4*)(part + i + (long)rg * PS);
    s += *(const f32x4*)(F2f + i);
    f32x4 r;
#pragma unroll
    for (int j = 0; j < 4; ++j) r[j] = s[j] > 0.f ? s[j] : 0.f;
    *(f32x4*)(out + i) = r;
}

// ---------------------------------------------------------------------------
extern "C" void kernel_launch(void* const* d_in, const int* in_sizes, int n_in,
                              void* d_out, int out_size, void* d_ws, size_t ws_size,
                              hipStream_t stream) {
    const float* F   = (const float*)d_in[0];   // [8][512][256]
    const float* adj = (const float*)d_in[1];   // [8][16][512][512]
    const float* Wr  = (const float*)d_in[2];   // [16][256][256]
    const float* W0  = (const float*)d_in[3];   // [256][256]
    float* out = (float*)d_out;                 // [8][512][256]

    unsigned short* wT  = (unsigned short*)d_ws;             // 17*256*256 bf16
    unsigned short* Fbf = wT + 17 * 256 * 256;               // 8*512*256 bf16
    unsigned short* FW  = Fbf + (long)8 * 512 * 256;         // 8*16*64*2048 bf16
    float* F2f  = (float*)(FW + (long)8 * 16 * 64 * 2048);   // 8*512*256 f32
    float* part = F2f + (long)8 * 512 * 256;                 // 8*8*512*256 f32

    k0_transpose<<<17 * 64, 256, 0, stream>>>(Wr, W0, wT);
    k0b_convF<<<512, 256, 0, stream>>>(F, Fbf);
    k1_fw<<<1088, 256, 0, stream>>>(Fbf, wT, FW, F2f);
    k2_main<<<512, 256, 0, stream>>>(adj, FW, part);
    k3_reduce<<<1024, 256, 0, stream>>>(part, F2f, out);
}